// Round 9
// baseline (479.780 us; speedup 1.0000x reference)
//
#include <hip/hip_runtime.h>
#include <hip/hip_bf16.h>
#include <hip/hip_fp16.h>

// ---------------- problem constants ----------------
constexpr int GT = 32768;          // B*T frames
constexpr int TSEQ = 32;

typedef _Float16 h2 __attribute__((ext_vector_type(2)));

#if defined(__has_builtin)
#if __has_builtin(__builtin_amdgcn_fdot2)
#define FDOT2(a, b, c) __builtin_amdgcn_fdot2((a), (b), (c), false)
#endif
#endif
#ifndef FDOT2
#define FDOT2(a, b, c) fmaf((float)(a).x, (float)(b).x, fmaf((float)(a).y, (float)(b).y, (c)))
#endif

__device__ __forceinline__ h2 pack2(float a, float b) {
  h2 v; v.x = (_Float16)a; v.y = (_Float16)b; return v;
}

// ---------------- workspace layout (4-byte slots; wsh = h2 view, ws = f32 view) -----
// obsTh  h2 [200][GT] @0          (ci2*100+pix; dead after conv1)
// pool1h h2 [200][GT] @6553600    (8 co-pairs x 25 pos; dead after conv2)
// pool2h h2 [64][GT]  @0          (q = co2*4+pos; dead after fc1)
// y1h    h2 [64][GT]  @2097152    (fc1 j-pairs; dead after fc2)
// featsh h2 [32][GT]  @4194304    (fc2 j-pairs)
// gx     f32 [32][1024][512] @6553600  (pool1h dead by then; ends 23330816 < WB)
constexpr size_t OBS_TH = 0;
constexpr size_t POOL1H = 6553600;
constexpr size_t POOL2H = 0;
constexpr size_t Y1H    = 2097152;
constexpr size_t FEATSH = 4194304;
constexpr size_t GX     = 6553600;
constexpr size_t WB     = 26214400;         // weights region (98016 slots)
constexpr size_t W_C1H  = WB + 0;           // 288  h2: [(ci2*9+t9)][16 co]
constexpr size_t W_C2H  = WB + 288;         // 2304 h2: [(ci2*9+t9)][32 co]
constexpr size_t W_F1H  = WB + 2592;        // 8192 h2: [q][128 j], BN folded
constexpr size_t B_F1   = WB + 10784;       // 128 fp32
constexpr size_t W_F2H  = WB + 10912;       // 4096 h2: [k2][64 j], BN folded
constexpr size_t B_F2   = WB + 15008;       // 64 fp32
constexpr size_t W_ENCXH= WB + 15072;       // 16384 h2: [k2][512 r], rows r=u*4+gate
constexpr size_t W_ENCHH= WB + 31456;       // 32768 h2: [k2][512 r]
constexpr size_t B_ENC  = WB + 64224;       // 512 fp32
constexpr size_t W_DECH = WB + 64736;       // 32768 h2: (dec_w_ih+dec_w_hh) [k2][512]
constexpr size_t B_DEC  = WB + 97504;       // 512 fp32

__device__ __forceinline__ float sigf(float x)  { return 1.f / (1.f + __expf(-x)); }
__device__ __forceinline__ float tanhfast(float x) { return 1.f - 2.f / (__expf(2.f * x) + 1.f); }

// ---------------- setup: transpose/fold/f16-pack weights (98016 items) ----------
__global__ __launch_bounds__(256) void k_setup(
    const float* __restrict__ c1w, const float* __restrict__ c2w,
    const float* __restrict__ f1w, const float* __restrict__ f1b,
    const float* __restrict__ g1, const float* __restrict__ be1,
    const float* __restrict__ m1, const float* __restrict__ v1,
    const float* __restrict__ f2w, const float* __restrict__ f2b,
    const float* __restrict__ g2, const float* __restrict__ be2,
    const float* __restrict__ m2, const float* __restrict__ v2,
    const float* __restrict__ ewih, const float* __restrict__ ewhh, const float* __restrict__ eb,
    const float* __restrict__ dwih, const float* __restrict__ dwhh, const float* __restrict__ db,
    float* __restrict__ ws) {
  h2* wsh = (h2*)ws;
  long i = (long)blockIdx.x * 256 + threadIdx.x;
  if (i < 288) { int co = i & 15, q = i >> 4; int ci2 = q / 9, t9 = q % 9;
    wsh[W_C1H + i] = pack2(c1w[co * 36 + 2 * ci2 * 9 + t9],
                           c1w[co * 36 + (2 * ci2 + 1) * 9 + t9]); return; }
  i -= 288;
  if (i < 2304) { int co = i & 31, q = i >> 5; int ci2 = q / 9, t9 = q % 9;
    wsh[W_C2H + i] = pack2(c2w[co * 144 + (2 * ci2) * 9 + t9],
                           c2w[co * 144 + (2 * ci2 + 1) * 9 + t9]); return; }
  i -= 2304;
  if (i < 8192) { int j = i & 127, q = i >> 7; int co2 = q >> 2, pos = q & 3;
    float s = g1[j] * rsqrtf(v1[j] + 1e-5f);
    wsh[W_F1H + i] = pack2(f1w[j * 128 + 8 * co2 + pos] * s,
                           f1w[j * 128 + 8 * co2 + 4 + pos] * s); return; }
  i -= 8192;
  if (i < 128) { int j = i; float s = g1[j] * rsqrtf(v1[j] + 1e-5f);
    ws[B_F1 + i] = (f1b[j] - m1[j]) * s + be1[j]; return; }
  i -= 128;
  if (i < 4096) { int j = i & 63, k2 = i >> 6;
    float s = g2[j] * rsqrtf(v2[j] + 1e-5f);
    wsh[W_F2H + i] = pack2(f2w[j * 128 + 2 * k2] * s,
                           f2w[j * 128 + 2 * k2 + 1] * s); return; }
  i -= 4096;
  if (i < 64) { int j = i; float s = g2[j] * rsqrtf(v2[j] + 1e-5f);
    ws[B_F2 + i] = (f2b[j] - m2[j]) * s + be2[j]; return; }
  i -= 64;
  if (i < 16384) { int r = i & 511, k2 = i >> 9;
    int u = r >> 2, gt = r & 3, jr = gt * 128 + u;
    wsh[W_ENCXH + i] = pack2(ewih[jr * 64 + 2 * k2], ewih[jr * 64 + 2 * k2 + 1]); return; }
  i -= 16384;
  if (i < 32768) { int r = i & 511, k2 = i >> 9;
    int u = r >> 2, gt = r & 3, jr = gt * 128 + u;
    wsh[W_ENCHH + i] = pack2(ewhh[jr * 128 + 2 * k2], ewhh[jr * 128 + 2 * k2 + 1]); return; }
  i -= 32768;
  if (i < 512) { int u = i >> 2, gt = i & 3; ws[B_ENC + i] = eb[gt * 128 + u]; return; }
  i -= 512;
  if (i < 32768) { int r = i & 511, k2 = i >> 9;
    int u = r >> 2, gt = r & 3, jr = gt * 128 + u;
    wsh[W_DECH + i] = pack2(dwih[jr * 128 + 2 * k2] + dwhh[jr * 128 + 2 * k2],
                            dwih[jr * 128 + 2 * k2 + 1] + dwhh[jr * 128 + 2 * k2 + 1]); return; }
  i -= 32768;
  if (i < 512) { int u = i >> 2, gt = i & 3; ws[B_DEC + i] = db[gt * 128 + u]; return; }
}

// ---------------- transpose+pack: obs [b][t*400+ci*100+pix] -> obsTh h2 [ci2*100+pix][t*1024+b]
__global__ __launch_bounds__(256) void k_transpose_pack(const float* __restrict__ obs,
                                                        h2* __restrict__ obsTh) {
  __shared__ float sm[2][4][4][64];   // [buf][ci][q][lane]
  const int pix0 = blockIdx.x * 4;    // 25 quads
  const int b0   = blockIdx.y * 64;   // 16 tiles
  const int lane = threadIdx.x & 63;
  const int grp  = threadIdx.x >> 6;  // 0..3
  const int ci2  = grp >> 1;
  const int q0   = (grp & 1) * 2;
  for (int t = 0; t < 32; ++t) {
    const int buf = t & 1;
    const float4 v = *(const float4*)(obs + (size_t)(b0 + lane) * 12800
                                      + t * 400 + grp * 100 + pix0);
    sm[buf][grp][0][lane] = v.x;
    sm[buf][grp][1][lane] = v.y;
    sm[buf][grp][2][lane] = v.z;
    sm[buf][grp][3][lane] = v.w;
    __syncthreads();
    #pragma unroll
    for (int qq = 0; qq < 2; ++qq) {
      const int q = q0 + qq;
      h2 val = pack2(sm[buf][2 * ci2][q][lane], sm[buf][2 * ci2 + 1][q][lane]);
      obsTh[(size_t)(ci2 * 100 + pix0 + q) * GT + t * 1024 + b0 + lane] = val;
    }
  }
}

// ---------------- conv1 (4->16) via dot2 over ci-pairs + relu + maxpool2 ------------
__global__ __launch_bounds__(256) void k_conv1h(const h2* __restrict__ obsTh,
                                                const h2* __restrict__ wch,
                                                const float* __restrict__ bias,
                                                h2* __restrict__ pool1h) {
  int g = blockIdx.x * 256 + threadIdx.x;
  int pos = blockIdx.y;               // 0..24
  int py = pos / 5, px = pos % 5;
  float acc[4][16];
  #pragma unroll
  for (int s = 0; s < 4; ++s)
    #pragma unroll
    for (int c = 0; c < 16; ++c) acc[s][c] = 0.f;
  const h2 hz = pack2(0.f, 0.f);

  #pragma unroll
  for (int ci2 = 0; ci2 < 2; ++ci2) {
    h2 p[16];
    #pragma unroll
    for (int r = 0; r < 4; ++r) {
      int iy = 2 * py + r - 1;
      #pragma unroll
      for (int cx = 0; cx < 4; ++cx) {
        int ix = 2 * px + cx - 1;
        bool ok = ((unsigned)iy < 10u) && ((unsigned)ix < 10u);   // wave-uniform
        p[r * 4 + cx] = ok ? obsTh[(size_t)(ci2 * 100 + iy * 10 + ix) * GT + g] : hz;
      }
    }
    #pragma unroll
    for (int t9 = 0; t9 < 9; ++t9) {
      int ky = t9 / 3, kx = t9 % 3;
      const h2* w = wch + ((ci2 * 9 + t9) << 4);
      h2 wv[16];
      #pragma unroll
      for (int c = 0; c < 16; ++c) wv[c] = w[c];
      #pragma unroll
      for (int dy = 0; dy < 2; ++dy)
        #pragma unroll
        for (int dx = 0; dx < 2; ++dx) {
          h2 xv = p[(dy + ky) * 4 + (dx + kx)];
          #pragma unroll
          for (int c = 0; c < 16; ++c)
            acc[dy * 2 + dx][c] = FDOT2(xv, wv[c], acc[dy * 2 + dx][c]);
        }
    }
  }
  float m[16];
  #pragma unroll
  for (int c = 0; c < 16; ++c) {
    float v = fmaxf(fmaxf(acc[0][c], acc[1][c]), fmaxf(acc[2][c], acc[3][c]));
    m[c] = fmaxf(v + bias[c], 0.f);
  }
  #pragma unroll
  for (int c2 = 0; c2 < 8; ++c2)
    pool1h[(size_t)(c2 * 25 + pos) * GT + g] = pack2(m[2 * c2], m[2 * c2 + 1]);
}

// ---------------- conv2 (16->32) dot2, 16 co/thread (half the patch re-reads) -------
__global__ __launch_bounds__(256) void k_conv2h(const h2* __restrict__ pool1h,
                                                const h2* __restrict__ wch,
                                                const float* __restrict__ bias,
                                                h2* __restrict__ pool2h) {
  int g = blockIdx.x * 256 + threadIdx.x;
  int pos = blockIdx.y & 3;
  int h = blockIdx.y >> 2;            // co half (0..1), 16 channels each
  int py = pos >> 1, px = pos & 1;
  float acc[4][16];
  #pragma unroll
  for (int s = 0; s < 4; ++s)
    #pragma unroll
    for (int c = 0; c < 16; ++c) acc[s][c] = 0.f;
  const h2 hz = pack2(0.f, 0.f);

  #pragma unroll 1
  for (int ci2 = 0; ci2 < 8; ++ci2) {
    h2 p[16];
    #pragma unroll
    for (int r = 0; r < 4; ++r) {
      int iy = 2 * py + r - 1;
      #pragma unroll
      for (int cx = 0; cx < 4; ++cx) {
        int ix = 2 * px + cx - 1;
        bool ok = ((unsigned)iy < 5u) && ((unsigned)ix < 5u);     // wave-uniform
        p[r * 4 + cx] = ok ? pool1h[(size_t)(ci2 * 25 + iy * 5 + ix) * GT + g] : hz;
      }
    }
    #pragma unroll
    for (int t9 = 0; t9 < 9; ++t9) {
      int ky = t9 / 3, kx = t9 % 3;
      const h2* w = wch + (ci2 * 9 + t9) * 32 + h * 16;
      h2 wv[16];
      #pragma unroll
      for (int c = 0; c < 16; ++c) wv[c] = w[c];
      #pragma unroll
      for (int dy = 0; dy < 2; ++dy)
        #pragma unroll
        for (int dx = 0; dx < 2; ++dx) {
          h2 xv = p[(dy + ky) * 4 + (dx + kx)];
          #pragma unroll
          for (int c = 0; c < 16; ++c)
            acc[dy * 2 + dx][c] = FDOT2(xv, wv[c], acc[dy * 2 + dx][c]);
        }
    }
  }
  float m[16];
  #pragma unroll
  for (int c = 0; c < 16; ++c) {
    float v = fmaxf(fmaxf(acc[0][c], acc[1][c]), fmaxf(acc[2][c], acc[3][c]));
    m[c] = fmaxf(v + bias[h * 16 + c], 0.f);
  }
  #pragma unroll
  for (int c2 = 0; c2 < 8; ++c2) {
    int q = (h * 8 + c2) * 4 + pos;   // co2*4 + pos
    pool2h[(size_t)q * GT + g] = pack2(m[2 * c2], m[2 * c2 + 1]);
  }
}

// ---------------- FC via dot2 (+folded BN) + relu, 32 j/block -----------------------
__global__ __launch_bounds__(256) void k_fc32h(const h2* __restrict__ x,
                                               const h2* __restrict__ WT,
                                               const float* __restrict__ bf,
                                               h2* __restrict__ y, int K2, int J) {
  int g = blockIdx.x * 256 + threadIdx.x;
  int j0 = blockIdx.y * 32;
  float acc[32];
  #pragma unroll
  for (int c = 0; c < 32; ++c) acc[c] = 0.f;
  for (int k2 = 0; k2 < K2; ++k2) {
    h2 xv = x[(size_t)k2 * GT + g];
    const h2* w = WT + (size_t)k2 * J + j0;
    #pragma unroll
    for (int c = 0; c < 32; ++c) acc[c] = FDOT2(xv, w[c], acc[c]);
  }
  #pragma unroll
  for (int c2 = 0; c2 < 16; ++c2) {
    float a = fmaxf(acc[2 * c2] + bf[j0 + 2 * c2], 0.f);
    float b = fmaxf(acc[2 * c2 + 1] + bf[j0 + 2 * c2 + 1], 0.f);
    y[(size_t)(j0 / 2 + c2) * GT + g] = pack2(a, b);
  }
}

// ---------------- encoder x-projection, dot2, 64 r/block; gx fp32 [t][b][512] -------
__global__ __launch_bounds__(256) void k_xgatesh(const h2* __restrict__ featsh,
                                                 const h2* __restrict__ wxh,
                                                 const float* __restrict__ br,
                                                 float* __restrict__ gx) {
  int t  = blockIdx.x >> 2;
  int bq = blockIdx.x & 3;
  int b  = bq * 256 + threadIdx.x;
  int r0 = blockIdx.y * 64;
  float acc[64];
  #pragma unroll
  for (int i = 0; i < 64; ++i) acc[i] = br[r0 + i];
  const h2* xcol = featsh + (size_t)t * 1024 + b;
  for (int k2 = 0; k2 < 32; ++k2) {
    h2 xv = xcol[(size_t)k2 * GT];
    const h2* w = wxh + k2 * 512 + r0;
    #pragma unroll
    for (int i = 0; i < 64; ++i) acc[i] = FDOT2(xv, w[i], acc[i]);
  }
  float* gxs = gx + (size_t)t * 524288 + (size_t)b * 512 + r0;
  #pragma unroll
  for (int i = 0; i < 64; ++i) gxs[i] = acc[i];
}

// ---------------- fused enc+dec+head: 512 blocks x 512 thr, 2 batch/block -----------
// 2 blocks/CU (16 waves/CU, 2x R8's TLP). Thread (kg=tid&7, g=tid>>3): gate rows
// r0=g*8..+7, k-pair slice [kg*8,+8) -> 64 h2 weight regs. Per step: 2 bl x 8 r x
// 8 pairs = 128 dot2. Reduce: xor1 (select bl=kg&1), xor2, xor4. Lanes kg<2 write h.
__global__ __launch_bounds__(512, 2) void k_seq7(
    const float* __restrict__ gx,
    const h2* __restrict__ WENCH, const h2* __restrict__ WDECH,
    const float* __restrict__ bdec,
    const float* __restrict__ ow, const float* __restrict__ ob,
    float* __restrict__ out) {
  const int tid = threadIdx.x;
  const int kg  = tid & 7;
  const int g   = tid >> 3;           // 0..63
  const int r0  = g * 8;
  const int blo = kg & 1;             // batch elem this lane finalizes
  const int bown = blockIdx.x * 2 + blo;

  __shared__ h2 hbufh[2][2 * 68];     // [buf][bl*68 + k2]
  __shared__ h2 owl2[12 * 68];

  for (int i = tid; i < 2 * 2 * 68; i += 512) ((h2*)hbufh)[i] = pack2(0.f, 0.f);
  for (int i = tid; i < 768; i += 512) {
    int o = i >> 6, k2 = i & 63;
    owl2[o * 68 + k2] = pack2(ow[o * 128 + 2 * k2], ow[o * 128 + 2 * k2 + 1]);
  }
  const float obv = (tid < 24) ? ob[tid >> 1] : 0.f;

  h2 wreg[64];                        // wreg[p*8+r] = W[(kg*8+p)][r0+r]
  #pragma unroll
  for (int p = 0; p < 8; ++p) {
    const h2* wp = WENCH + (size_t)(kg * 8 + p) * 512 + r0;
    *(uint4*)&wreg[p * 8]     = *(const uint4*)wp;
    *(uint4*)&wreg[p * 8 + 4] = *(const uint4*)(wp + 4);
  }

  float c0 = 0.f, c1 = 0.f;
  const int rdofs = kg * 8;
  const int wrofs = blo * 68 + g;
  __syncthreads();

  int cur = 0;

  // ================= encoder: 32 steps =================
  for (int t = 0; t < TSEQ; ++t) {
    const float* gb0 = gx + (size_t)t * 524288 + (size_t)bown * 512 + r0;
    const float4 ga = *(const float4*)gb0;
    const float4 gb = *(const float4*)(gb0 + 4);

    float acc[2][8];
    #pragma unroll
    for (int bl = 0; bl < 2; ++bl)
      #pragma unroll
      for (int r = 0; r < 8; ++r) acc[bl][r] = 0.f;

    const h2* hc = &hbufh[cur][0];
    h2 hv0[8], hv1[8];
    *(uint4*)&hv0[0] = *(const uint4*)&hc[rdofs];
    *(uint4*)&hv0[4] = *(const uint4*)&hc[rdofs + 4];
    *(uint4*)&hv1[0] = *(const uint4*)&hc[68 + rdofs];
    *(uint4*)&hv1[4] = *(const uint4*)&hc[68 + rdofs + 4];
    #pragma unroll
    for (int p = 0; p < 8; ++p) {
      #pragma unroll
      for (int r = 0; r < 8; ++r) {
        acc[0][r] = FDOT2(hv0[p], wreg[p * 8 + r], acc[0][r]);
        acc[1][r] = FDOT2(hv1[p], wreg[p * 8 + r], acc[1][r]);
      }
    }
    float D[8];
    #pragma unroll
    for (int r = 0; r < 8; ++r) {
      float a0 = acc[0][r] + __shfl_xor(acc[0][r], 1, 64);
      float a1 = acc[1][r] + __shfl_xor(acc[1][r], 1, 64);
      float s  = blo ? a1 : a0;
      s += __shfl_xor(s, 2, 64);
      s += __shfl_xor(s, 4, 64);
      D[r] = s;
    }
    const float gi0 = D[0] + ga.x, gf0 = D[1] + ga.y, gg0 = D[2] + ga.z, go0 = D[3] + ga.w;
    const float gi1 = D[4] + gb.x, gf1 = D[5] + gb.y, gg1 = D[6] + gb.z, go1 = D[7] + gb.w;
    c0 = sigf(gf0) * c0 + sigf(gi0) * tanhfast(gg0);
    c1 = sigf(gf1) * c1 + sigf(gi1) * tanhfast(gg1);
    const float hn0 = sigf(go0) * tanhfast(c0);
    const float hn1 = sigf(go1) * tanhfast(c1);
    if (kg < 2) hbufh[cur ^ 1][wrofs] = pack2(hn0, hn1);
    __syncthreads();
    cur ^= 1;
  }

  // ---- swap in decoder weights (x_in == h => W = W_ih + W_hh, pre-summed) ----
  #pragma unroll
  for (int p = 0; p < 8; ++p) {
    const h2* wp = WDECH + (size_t)(kg * 8 + p) * 512 + r0;
    *(uint4*)&wreg[p * 8]     = *(const uint4*)wp;
    *(uint4*)&wreg[p * 8 + 4] = *(const uint4*)(wp + 4);
  }
  const float4 bda = *(const float4*)(bdec + r0);
  const float4 bdb = *(const float4*)(bdec + r0 + 4);

  // ================= decoder: 10 steps + fused head =================
  for (int t = 0; t < 10; ++t) {
    float acc[2][8];
    #pragma unroll
    for (int bl = 0; bl < 2; ++bl)
      #pragma unroll
      for (int r = 0; r < 8; ++r) acc[bl][r] = 0.f;

    const h2* hc = &hbufh[cur][0];
    h2 hv0[8], hv1[8];
    *(uint4*)&hv0[0] = *(const uint4*)&hc[rdofs];
    *(uint4*)&hv0[4] = *(const uint4*)&hc[rdofs + 4];
    *(uint4*)&hv1[0] = *(const uint4*)&hc[68 + rdofs];
    *(uint4*)&hv1[4] = *(const uint4*)&hc[68 + rdofs + 4];
    #pragma unroll
    for (int p = 0; p < 8; ++p) {
      #pragma unroll
      for (int r = 0; r < 8; ++r) {
        acc[0][r] = FDOT2(hv0[p], wreg[p * 8 + r], acc[0][r]);
        acc[1][r] = FDOT2(hv1[p], wreg[p * 8 + r], acc[1][r]);
      }
    }
    float D[8];
    #pragma unroll
    for (int r = 0; r < 8; ++r) {
      float a0 = acc[0][r] + __shfl_xor(acc[0][r], 1, 64);
      float a1 = acc[1][r] + __shfl_xor(acc[1][r], 1, 64);
      float s  = blo ? a1 : a0;
      s += __shfl_xor(s, 2, 64);
      s += __shfl_xor(s, 4, 64);
      D[r] = s;
    }
    const float gi0 = D[0] + bda.x, gf0 = D[1] + bda.y, gg0 = D[2] + bda.z, go0 = D[3] + bda.w;
    const float gi1 = D[4] + bdb.x, gf1 = D[5] + bdb.y, gg1 = D[6] + bdb.z, go1 = D[7] + bdb.w;
    c0 = sigf(gf0) * c0 + sigf(gi0) * tanhfast(gg0);
    c1 = sigf(gf1) * c1 + sigf(gi1) * tanhfast(gg1);
    const float hn0 = sigf(go0) * tanhfast(c0);
    const float hn1 = sigf(go1) * tanhfast(c1);
    if (kg < 2) hbufh[cur ^ 1][wrofs] = pack2(hn0, hn1);
    __syncthreads();
    cur ^= 1;
    // output head: tid<24 (o = tid>>1, bl = tid&1), LDS-only reads of new h
    if (tid < 24) {
      const int o  = tid >> 1;
      const int bh = tid & 1;
      const h2* hh = &hbufh[cur][bh * 68];
      const h2* wo = &owl2[o * 68];
      float oacc = obv;
      #pragma unroll
      for (int k2 = 0; k2 < 64; ++k2) oacc = FDOT2(hh[k2], wo[k2], oacc);
      out[(blockIdx.x * 2 + bh) * 120 + t * 12 + o] = oacc;
    }
  }
}

// ---------------- launch ----------------
extern "C" void kernel_launch(void* const* d_in, const int* in_sizes, int n_in,
                              void* d_out, int out_size, void* d_ws, size_t ws_size,
                              hipStream_t stream) {
  const float* obs  = (const float*)d_in[0];
  const float* c1w  = (const float*)d_in[1];
  const float* c1b  = (const float*)d_in[2];
  const float* c2w  = (const float*)d_in[3];
  const float* c2b  = (const float*)d_in[4];
  const float* f1w  = (const float*)d_in[5];
  const float* f1b  = (const float*)d_in[6];
  const float* g1   = (const float*)d_in[7];
  const float* be1  = (const float*)d_in[8];
  const float* m1   = (const float*)d_in[9];
  const float* v1   = (const float*)d_in[10];
  const float* f2w  = (const float*)d_in[11];
  const float* f2b  = (const float*)d_in[12];
  const float* g2   = (const float*)d_in[13];
  const float* be2  = (const float*)d_in[14];
  const float* m2   = (const float*)d_in[15];
  const float* v2   = (const float*)d_in[16];
  const float* ewih = (const float*)d_in[17];
  const float* ewhh = (const float*)d_in[18];
  const float* eb   = (const float*)d_in[19];
  const float* dwih = (const float*)d_in[20];
  const float* dwhh = (const float*)d_in[21];
  const float* db   = (const float*)d_in[22];
  const float* ow   = (const float*)d_in[23];
  const float* ob   = (const float*)d_in[24];
  float* ws  = (float*)d_ws;
  h2*    wsh = (h2*)d_ws;
  float* out = (float*)d_out;

  // weight prep: 98016 items = 383 blocks x 256
  k_setup<<<383, 256, 0, stream>>>(c1w, c2w, f1w, f1b, g1, be1, m1, v1,
                                   f2w, f2b, g2, be2, m2, v2,
                                   ewih, ewhh, eb, dwih, dwhh, db, ws);
  k_transpose_pack<<<dim3(25, 16), 256, 0, stream>>>(obs, wsh + OBS_TH);
  k_conv1h<<<dim3(128, 25), 256, 0, stream>>>(wsh + OBS_TH, wsh + W_C1H, c1b, wsh + POOL1H);
  k_conv2h<<<dim3(128, 8), 256, 0, stream>>>(wsh + POOL1H, wsh + W_C2H, c2b, wsh + POOL2H);
  k_fc32h<<<dim3(128, 4), 256, 0, stream>>>(wsh + POOL2H, wsh + W_F1H, ws + B_F1,
                                            wsh + Y1H, 64, 128);
  k_fc32h<<<dim3(128, 2), 256, 0, stream>>>(wsh + Y1H, wsh + W_F2H, ws + B_F2,
                                            wsh + FEATSH, 64, 64);
  k_xgatesh<<<dim3(128, 8), 256, 0, stream>>>(wsh + FEATSH, wsh + W_ENCXH, ws + B_ENC,
                                              ws + GX);
  // fused encoder + decoder + output head: 2 batch/block x 512 blocks
  k_seq7<<<512, 512, 0, stream>>>(ws + GX, wsh + W_ENCHH, wsh + W_DECH,
                                  ws + B_DEC, ow, ob, out);
}

// Round 10
// 388.942 us; speedup vs baseline: 1.2336x; 1.2336x over previous
//
#include <hip/hip_runtime.h>
#include <hip/hip_bf16.h>
#include <hip/hip_fp16.h>

// ---------------- problem constants ----------------
constexpr int GT = 32768;          // B*T frames
constexpr int TSEQ = 32;

typedef _Float16 h2 __attribute__((ext_vector_type(2)));

#if defined(__has_builtin)
#if __has_builtin(__builtin_amdgcn_fdot2)
#define FDOT2(a, b, c) __builtin_amdgcn_fdot2((a), (b), (c), false)
#endif
#endif
#ifndef FDOT2
#define FDOT2(a, b, c) fmaf((float)(a).x, (float)(b).x, fmaf((float)(a).y, (float)(b).y, (c)))
#endif

__device__ __forceinline__ h2 pack2(float a, float b) {
  h2 v; v.x = (_Float16)a; v.y = (_Float16)b; return v;
}

// ---------------- workspace layout (4-byte slots; wsh = h2 view, ws = f32 view) -----
// (identical to R8 — the 409 us configuration)
constexpr size_t OBS_T  = 0;
constexpr size_t POOL1H = 13107200;
constexpr size_t POOL2H = 0;
constexpr size_t Y1H    = 2097152;
constexpr size_t FEATSH = 19660800;
constexpr size_t GX     = 0;
constexpr size_t WB     = 26214400;
constexpr size_t W_C1   = WB + 0;           // 576  fp32: conv1 wT [36][16]
constexpr size_t W_C2H  = WB + 576;         // 2304 h2: [(ci2*9+t9)][32 co]
constexpr size_t W_F1H  = WB + 2880;        // 8192 h2: [q=co2*4+pos][128 j], BN folded
constexpr size_t B_F1   = WB + 11072;       // 128 fp32
constexpr size_t W_F2H  = WB + 11200;       // 4096 h2: [k2][64 j], BN folded
constexpr size_t B_F2   = WB + 15296;       // 64 fp32
constexpr size_t W_ENCXH= WB + 15360;       // 16384 h2: [k2][512 r], rows r=u*4+gate
constexpr size_t W_ENCHH= WB + 31744;       // 32768 h2: [k2][512 r]
constexpr size_t B_ENC  = WB + 64512;       // 512 fp32
constexpr size_t W_DECH = WB + 65024;       // 32768 h2: (dec_w_ih+dec_w_hh) [k2][512]
constexpr size_t B_DEC  = WB + 97792;       // 512 fp32

__device__ __forceinline__ float sigf(float x)  { return 1.f / (1.f + __expf(-x)); }
__device__ __forceinline__ float tanhfast(float x) { return 1.f - 2.f / (__expf(2.f * x) + 1.f); }

// ---------------- setup: transpose/fold/f16-pack weights (98304 items) ----------
__global__ __launch_bounds__(256) void k_setup(
    const float* __restrict__ c1w, const float* __restrict__ c2w,
    const float* __restrict__ f1w, const float* __restrict__ f1b,
    const float* __restrict__ g1, const float* __restrict__ be1,
    const float* __restrict__ m1, const float* __restrict__ v1,
    const float* __restrict__ f2w, const float* __restrict__ f2b,
    const float* __restrict__ g2, const float* __restrict__ be2,
    const float* __restrict__ m2, const float* __restrict__ v2,
    const float* __restrict__ ewih, const float* __restrict__ ewhh, const float* __restrict__ eb,
    const float* __restrict__ dwih, const float* __restrict__ dwhh, const float* __restrict__ db,
    float* __restrict__ ws) {
  h2* wsh = (h2*)ws;
  long i = (long)blockIdx.x * 256 + threadIdx.x;
  if (i < 576)  { int c = i & 15, r = i >> 4; ws[W_C1 + i] = c1w[c * 36 + r]; return; }
  i -= 576;
  if (i < 2304) { int co = i & 31, q = i >> 5; int ci2 = q / 9, t9 = q % 9;
    wsh[W_C2H + i] = pack2(c2w[co * 144 + (2 * ci2) * 9 + t9],
                           c2w[co * 144 + (2 * ci2 + 1) * 9 + t9]); return; }
  i -= 2304;
  if (i < 8192) { int j = i & 127, q = i >> 7; int co2 = q >> 2, pos = q & 3;
    float s = g1[j] * rsqrtf(v1[j] + 1e-5f);
    wsh[W_F1H + i] = pack2(f1w[j * 128 + 8 * co2 + pos] * s,
                           f1w[j * 128 + 8 * co2 + 4 + pos] * s); return; }
  i -= 8192;
  if (i < 128) { int j = i; float s = g1[j] * rsqrtf(v1[j] + 1e-5f);
    ws[B_F1 + i] = (f1b[j] - m1[j]) * s + be1[j]; return; }
  i -= 128;
  if (i < 4096) { int j = i & 63, k2 = i >> 6;
    float s = g2[j] * rsqrtf(v2[j] + 1e-5f);
    wsh[W_F2H + i] = pack2(f2w[j * 128 + 2 * k2] * s,
                           f2w[j * 128 + 2 * k2 + 1] * s); return; }
  i -= 4096;
  if (i < 64) { int j = i; float s = g2[j] * rsqrtf(v2[j] + 1e-5f);
    ws[B_F2 + i] = (f2b[j] - m2[j]) * s + be2[j]; return; }
  i -= 64;
  if (i < 16384) { int r = i & 511, k2 = i >> 9;
    int u = r >> 2, gt = r & 3, jr = gt * 128 + u;
    wsh[W_ENCXH + i] = pack2(ewih[jr * 64 + 2 * k2], ewih[jr * 64 + 2 * k2 + 1]); return; }
  i -= 16384;
  if (i < 32768) { int r = i & 511, k2 = i >> 9;
    int u = r >> 2, gt = r & 3, jr = gt * 128 + u;
    wsh[W_ENCHH + i] = pack2(ewhh[jr * 128 + 2 * k2], ewhh[jr * 128 + 2 * k2 + 1]); return; }
  i -= 32768;
  if (i < 512) { int u = i >> 2, gt = i & 3; ws[B_ENC + i] = eb[gt * 128 + u]; return; }
  i -= 512;
  if (i < 32768) { int r = i & 511, k2 = i >> 9;
    int u = r >> 2, gt = r & 3, jr = gt * 128 + u;
    wsh[W_DECH + i] = pack2(dwih[jr * 128 + 2 * k2] + dwhh[jr * 128 + 2 * k2],
                            dwih[jr * 128 + 2 * k2 + 1] + dwhh[jr * 128 + 2 * k2 + 1]); return; }
  i -= 32768;
  if (i < 512) { int u = i >> 2, gt = i & 3; ws[B_DEC + i] = db[gt * 128 + u]; return; }
}

// ---------------- transpose obs [b][tp] -> obsT [p][t][b], float4 loads ----------------
__global__ __launch_bounds__(256) void k_transpose(const float* __restrict__ obs,
                                                   float* __restrict__ obsT) {
  __shared__ float tile[64][65];
  int tp0 = blockIdx.x * 64;
  int b0  = blockIdx.y * 64;
  int q     = threadIdx.x & 15;
  int rbase = threadIdx.x >> 4;
  #pragma unroll
  for (int rr = 0; rr < 4; ++rr) {
    int row = rbase + rr * 16;
    const float4 v = *(const float4*)(obs + (size_t)(b0 + row) * 12800 + tp0 + q * 4);
    tile[row][q * 4 + 0] = v.x;
    tile[row][q * 4 + 1] = v.y;
    tile[row][q * 4 + 2] = v.z;
    tile[row][q * 4 + 3] = v.w;
  }
  __syncthreads();
  int lane = threadIdx.x & 63;
  int grp  = threadIdx.x >> 6;
  for (int cc = 0; cc < 16; ++cc) {
    int col = grp * 16 + cc;
    int tp = tp0 + col;
    int t = tp / 400, p = tp % 400;
    obsT[(size_t)p * GT + t * 1024 + b0 + lane] = tile[lane][col];
  }
}

// ---------------- conv1 (4->16, fp32 math) + relu + maxpool2; writes f16 co-pairs ----
__global__ __launch_bounds__(256) void k_conv1(const float* __restrict__ obsT,
                                               const float* __restrict__ wT,
                                               const float* __restrict__ bias,
                                               h2* __restrict__ pool1h) {
  int g = blockIdx.x * 256 + threadIdx.x;
  int pos = blockIdx.y;
  int py = pos / 5, px = pos % 5;
  float acc[4][16];
  #pragma unroll
  for (int s = 0; s < 4; ++s)
    #pragma unroll
    for (int c = 0; c < 16; ++c) acc[s][c] = 0.f;

  #pragma unroll 1
  for (int ci = 0; ci < 4; ++ci) {
    float p[16];
    #pragma unroll
    for (int r = 0; r < 4; ++r) {
      int iy = 2 * py + r - 1;
      #pragma unroll
      for (int cx = 0; cx < 4; ++cx) {
        int ix = 2 * px + cx - 1;
        bool ok = ((unsigned)iy < 10u) && ((unsigned)ix < 10u);   // wave-uniform
        p[r * 4 + cx] = ok ? obsT[(size_t)(ci * 100 + iy * 10 + ix) * GT + g] : 0.f;
      }
    }
    #pragma unroll
    for (int t9 = 0; t9 < 9; ++t9) {
      int ky = t9 / 3, kx = t9 % 3;
      const float* w = wT + ((ci * 9 + t9) << 4);
      float wv[16];
      #pragma unroll
      for (int c = 0; c < 16; ++c) wv[c] = w[c];
      #pragma unroll
      for (int dy = 0; dy < 2; ++dy)
        #pragma unroll
        for (int dx = 0; dx < 2; ++dx) {
          float xv = p[(dy + ky) * 4 + (dx + kx)];
          #pragma unroll
          for (int c = 0; c < 16; ++c)
            acc[dy * 2 + dx][c] = fmaf(wv[c], xv, acc[dy * 2 + dx][c]);
        }
    }
  }
  float m[16];
  #pragma unroll
  for (int c = 0; c < 16; ++c) {
    float v = fmaxf(fmaxf(acc[0][c], acc[1][c]), fmaxf(acc[2][c], acc[3][c]));
    m[c] = fmaxf(v + bias[c], 0.f);
  }
  #pragma unroll
  for (int c2 = 0; c2 < 8; ++c2)
    pool1h[(size_t)(c2 * 25 + pos) * GT + g] = pack2(m[2 * c2], m[2 * c2 + 1]);
}

// ---------------- conv2 (16->32) via f16 dot2 over ci-pairs; writes q=co2*4+pos ------
__global__ __launch_bounds__(256) void k_conv2h(const h2* __restrict__ pool1h,
                                                const h2* __restrict__ wch,
                                                const float* __restrict__ bias,
                                                h2* __restrict__ pool2h) {
  int g = blockIdx.x * 256 + threadIdx.x;
  int pos = blockIdx.y & 3;
  int h = blockIdx.y >> 2;              // co quarter (0..3), 8 channels each
  int py = pos >> 1, px = pos & 1;
  float acc[4][8];
  #pragma unroll
  for (int s = 0; s < 4; ++s)
    #pragma unroll
    for (int c = 0; c < 8; ++c) acc[s][c] = 0.f;
  const h2 hz = pack2(0.f, 0.f);

  #pragma unroll 1
  for (int ci2 = 0; ci2 < 8; ++ci2) {
    h2 p[16];
    #pragma unroll
    for (int r = 0; r < 4; ++r) {
      int iy = 2 * py + r - 1;
      #pragma unroll
      for (int cx = 0; cx < 4; ++cx) {
        int ix = 2 * px + cx - 1;
        bool ok = ((unsigned)iy < 5u) && ((unsigned)ix < 5u);     // wave-uniform
        p[r * 4 + cx] = ok ? pool1h[(size_t)(ci2 * 25 + iy * 5 + ix) * GT + g] : hz;
      }
    }
    #pragma unroll
    for (int t9 = 0; t9 < 9; ++t9) {
      int ky = t9 / 3, kx = t9 % 3;
      const h2* w = wch + (ci2 * 9 + t9) * 32 + h * 8;
      h2 wv[8];
      #pragma unroll
      for (int c = 0; c < 8; ++c) wv[c] = w[c];
      #pragma unroll
      for (int dy = 0; dy < 2; ++dy)
        #pragma unroll
        for (int dx = 0; dx < 2; ++dx) {
          h2 xv = p[(dy + ky) * 4 + (dx + kx)];
          #pragma unroll
          for (int c = 0; c < 8; ++c)
            acc[dy * 2 + dx][c] = FDOT2(xv, wv[c], acc[dy * 2 + dx][c]);
        }
    }
  }
  float m[8];
  #pragma unroll
  for (int c = 0; c < 8; ++c) {
    float v = fmaxf(fmaxf(acc[0][c], acc[1][c]), fmaxf(acc[2][c], acc[3][c]));
    m[c] = fmaxf(v + bias[h * 8 + c], 0.f);
  }
  #pragma unroll
  for (int c2 = 0; c2 < 4; ++c2) {
    int q = (h * 4 + c2) * 4 + pos;     // co2*4 + pos
    pool2h[(size_t)q * GT + g] = pack2(m[2 * c2], m[2 * c2 + 1]);
  }
}

// ---------------- FC via f16 dot2 (+folded BN) + relu; writes packed j-pairs --------
__global__ __launch_bounds__(256) void k_fc16h(const h2* __restrict__ x,
                                               const h2* __restrict__ WT,
                                               const float* __restrict__ bf,
                                               h2* __restrict__ y, int K2, int J) {
  int g = blockIdx.x * 256 + threadIdx.x;
  int j0 = blockIdx.y * 16;
  float acc[16];
  #pragma unroll
  for (int c = 0; c < 16; ++c) acc[c] = 0.f;
  for (int k2 = 0; k2 < K2; ++k2) {
    h2 xv = x[(size_t)k2 * GT + g];
    const h2* w = WT + (size_t)k2 * J + j0;
    #pragma unroll
    for (int c = 0; c < 16; ++c) acc[c] = FDOT2(xv, w[c], acc[c]);
  }
  #pragma unroll
  for (int c2 = 0; c2 < 8; ++c2) {
    float a = fmaxf(acc[2 * c2] + bf[j0 + 2 * c2], 0.f);
    float b = fmaxf(acc[2 * c2 + 1] + bf[j0 + 2 * c2 + 1], 0.f);
    y[(size_t)(j0 / 2 + c2) * GT + g] = pack2(a, b);
  }
}

// ---------------- encoder x-projection, f16 dot2; gx fp32 [t][b][512] ----------------
__global__ __launch_bounds__(256) void k_xgatesh(const h2* __restrict__ featsh,
                                                 const h2* __restrict__ wxh,
                                                 const float* __restrict__ br,
                                                 float* __restrict__ gx) {
  int t  = blockIdx.x >> 2;
  int bq = blockIdx.x & 3;
  int b  = bq * 256 + threadIdx.x;
  int r0 = blockIdx.y * 32;
  float acc[32];
  #pragma unroll
  for (int i = 0; i < 32; ++i) acc[i] = br[r0 + i];
  const h2* xcol = featsh + (size_t)t * 1024 + b;
  for (int k2 = 0; k2 < 32; ++k2) {
    h2 xv = xcol[(size_t)k2 * GT];
    const h2* w = wxh + k2 * 512 + r0;
    #pragma unroll
    for (int i = 0; i < 32; ++i) acc[i] = FDOT2(xv, w[i], acc[i]);
  }
  float* gxs = gx + (size_t)t * 524288 + (size_t)b * 512 + r0;
  #pragma unroll
  for (int i = 0; i < 32; ++i) gxs[i] = acc[i];
}

// ---------------- fused enc+dec+head: LDS-swizzled weights, 2-way k-split -----------
// 256 blocks x 512 threads, 4 batch/block. Thread (bl=tid&3, kg=(tid>>2)&1, g=tid>>3):
// gate rows r0=g*8..+7, k-pair slice [kg*32, +32). Per step: 8 r x 32 k2 = 256 dot2.
// Weights live in LDS: two 64KB regions (A = rows r0..r0+3 halves, B = rows r0+4..+7),
// chunk index c = p*128 + kg*64 + g, 16B lines -> lane-linear, 2-way banks = free.
// 4 bl lanes broadcast-share each weight chunk. Reduce: ONE shfl_xor(4) round.
// h double-buffered in LDS (h2, stride 68). One barrier per step.
__global__ __launch_bounds__(512, 2) void k_seq8(
    const float* __restrict__ gx,
    const h2* __restrict__ WENCH, const h2* __restrict__ WDECH,
    const float* __restrict__ bdec,
    const float* __restrict__ ow, const float* __restrict__ ob,
    float* __restrict__ out) {
  const int tid = threadIdx.x;
  const int bl  = tid & 3;
  const int kg  = (tid >> 2) & 1;
  const int g   = tid >> 3;           // 0..63
  const int r0  = g * 8;
  const int bown = blockIdx.x * 4 + bl;

  __shared__ h2 wA[16384];            // 64KB: [c=p*128+kg*64+g][4 h2] rows r0..r0+3
  __shared__ h2 wB[16384];            // 64KB: rows r0+4..r0+7
  __shared__ h2 hbufh[2][4 * 68];     // [buf][bl*68 + j]
  __shared__ h2 owl2[12 * 68];

  for (int i = tid; i < 2 * 4 * 68; i += 512) ((h2*)hbufh)[i] = pack2(0.f, 0.f);
  for (int i = tid; i < 768; i += 512) {
    int o = i >> 6, k2 = i & 63;
    owl2[o * 68 + k2] = pack2(ow[o * 128 + 2 * k2], ow[o * 128 + 2 * k2 + 1]);
  }
  const float obv = (tid < 48) ? ob[tid >> 2] : 0.f;

  // ---- stage ENC h-weights into swizzled LDS (once) ----
  for (int c = tid; c < 4096; c += 512) {
    int p = c >> 7, kgc = (c >> 6) & 1, gc = c & 63;
    const uint4* gp = (const uint4*)(WENCH + (size_t)(kgc * 32 + p) * 512 + gc * 8);
    *(uint4*)&wA[(size_t)c * 4] = gp[0];
    *(uint4*)&wB[(size_t)c * 4] = gp[1];
  }

  float c0 = 0.f, c1 = 0.f;
  const h2* wAp = &wA[(kg * 64 + g) * 4];
  const h2* wBp = &wB[(kg * 64 + g) * 4];
  __syncthreads();

  int cur = 0;

  // ================= encoder: 32 steps =================
  for (int t = 0; t < TSEQ; ++t) {
    const float* gb0 = gx + (size_t)t * 524288 + (size_t)bown * 512 + r0;
    const float4 ga = *(const float4*)gb0;
    const float4 gb = *(const float4*)(gb0 + 4);

    float acc[8];
    #pragma unroll
    for (int r = 0; r < 8; ++r) acc[r] = 0.f;

    const h2* hp = &hbufh[cur][bl * 68 + kg * 32];
    #pragma unroll
    for (int pc = 0; pc < 8; ++pc) {
      h2 hh[4];
      *(uint4*)hh = *(const uint4*)&hp[pc * 4];
      #pragma unroll
      for (int j = 0; j < 4; ++j) {
        const int p = pc * 4 + j;
        h2 wa[4], wb[4];
        *(uint4*)wa = *(const uint4*)&wAp[p * 512];
        *(uint4*)wb = *(const uint4*)&wBp[p * 512];
        acc[0] = FDOT2(hh[j], wa[0], acc[0]);
        acc[1] = FDOT2(hh[j], wa[1], acc[1]);
        acc[2] = FDOT2(hh[j], wa[2], acc[2]);
        acc[3] = FDOT2(hh[j], wa[3], acc[3]);
        acc[4] = FDOT2(hh[j], wb[0], acc[4]);
        acc[5] = FDOT2(hh[j], wb[1], acc[5]);
        acc[6] = FDOT2(hh[j], wb[2], acc[6]);
        acc[7] = FDOT2(hh[j], wb[3], acc[7]);
      }
    }
    float D[8];
    #pragma unroll
    for (int r = 0; r < 8; ++r) D[r] = acc[r] + __shfl_xor(acc[r], 4, 64);

    const float gi0 = D[0] + ga.x, gf0 = D[1] + ga.y, gg0 = D[2] + ga.z, go0 = D[3] + ga.w;
    const float gi1 = D[4] + gb.x, gf1 = D[5] + gb.y, gg1 = D[6] + gb.z, go1 = D[7] + gb.w;
    c0 = sigf(gf0) * c0 + sigf(gi0) * tanhfast(gg0);
    c1 = sigf(gf1) * c1 + sigf(gi1) * tanhfast(gg1);
    const float hn0 = sigf(go0) * tanhfast(c0);
    const float hn1 = sigf(go1) * tanhfast(c1);
    if (kg == 0) hbufh[cur ^ 1][bl * 68 + g] = pack2(hn0, hn1);
    __syncthreads();
    cur ^= 1;
  }

  // ---- swap in DEC weights (x_in == h => W = W_ih + W_hh, pre-summed) ----
  for (int c = tid; c < 4096; c += 512) {
    int p = c >> 7, kgc = (c >> 6) & 1, gc = c & 63;
    const uint4* gp = (const uint4*)(WDECH + (size_t)(kgc * 32 + p) * 512 + gc * 8);
    *(uint4*)&wA[(size_t)c * 4] = gp[0];
    *(uint4*)&wB[(size_t)c * 4] = gp[1];
  }
  const float4 bda = *(const float4*)(bdec + r0);
  const float4 bdb = *(const float4*)(bdec + r0 + 4);
  __syncthreads();

  // ================= decoder: 10 steps + fused head =================
  for (int t = 0; t < 10; ++t) {
    float acc[8];
    #pragma unroll
    for (int r = 0; r < 8; ++r) acc[r] = 0.f;

    const h2* hp = &hbufh[cur][bl * 68 + kg * 32];
    #pragma unroll
    for (int pc = 0; pc < 8; ++pc) {
      h2 hh[4];
      *(uint4*)hh = *(const uint4*)&hp[pc * 4];
      #pragma unroll
      for (int j = 0; j < 4; ++j) {
        const int p = pc * 4 + j;
        h2 wa[4], wb[4];
        *(uint4*)wa = *(const uint4*)&wAp[p * 512];
        *(uint4*)wb = *(const uint4*)&wBp[p * 512];
        acc[0] = FDOT2(hh[j], wa[0], acc[0]);
        acc[1] = FDOT2(hh[j], wa[1], acc[1]);
        acc[2] = FDOT2(hh[j], wa[2], acc[2]);
        acc[3] = FDOT2(hh[j], wa[3], acc[3]);
        acc[4] = FDOT2(hh[j], wb[0], acc[4]);
        acc[5] = FDOT2(hh[j], wb[1], acc[5]);
        acc[6] = FDOT2(hh[j], wb[2], acc[6]);
        acc[7] = FDOT2(hh[j], wb[3], acc[7]);
      }
    }
    float D[8];
    #pragma unroll
    for (int r = 0; r < 8; ++r) D[r] = acc[r] + __shfl_xor(acc[r], 4, 64);

    const float gi0 = D[0] + bda.x, gf0 = D[1] + bda.y, gg0 = D[2] + bda.z, go0 = D[3] + bda.w;
    const float gi1 = D[4] + bdb.x, gf1 = D[5] + bdb.y, gg1 = D[6] + bdb.z, go1 = D[7] + bdb.w;
    c0 = sigf(gf0) * c0 + sigf(gi0) * tanhfast(gg0);
    c1 = sigf(gf1) * c1 + sigf(gi1) * tanhfast(gg1);
    const float hn0 = sigf(go0) * tanhfast(c0);
    const float hn1 = sigf(go1) * tanhfast(c1);
    if (kg == 0) hbufh[cur ^ 1][bl * 68 + g] = pack2(hn0, hn1);
    __syncthreads();
    cur ^= 1;
    // output head: tid<48 (o = tid>>2, bl = tid&3), LDS-only reads of new h
    if (tid < 48) {
      const int o  = tid >> 2;
      const int bh = tid & 3;
      const h2* hh = &hbufh[cur][bh * 68];
      const h2* wo = &owl2[o * 68];
      float oacc = obv;
      #pragma unroll
      for (int k2 = 0; k2 < 64; ++k2) oacc = FDOT2(hh[k2], wo[k2], oacc);
      out[(blockIdx.x * 4 + bh) * 120 + t * 12 + o] = oacc;
    }
  }
}

// ---------------- launch ----------------
extern "C" void kernel_launch(void* const* d_in, const int* in_sizes, int n_in,
                              void* d_out, int out_size, void* d_ws, size_t ws_size,
                              hipStream_t stream) {
  const float* obs  = (const float*)d_in[0];
  const float* c1w  = (const float*)d_in[1];
  const float* c1b  = (const float*)d_in[2];
  const float* c2w  = (const float*)d_in[3];
  const float* c2b  = (const float*)d_in[4];
  const float* f1w  = (const float*)d_in[5];
  const float* f1b  = (const float*)d_in[6];
  const float* g1   = (const float*)d_in[7];
  const float* be1  = (const float*)d_in[8];
  const float* m1   = (const float*)d_in[9];
  const float* v1   = (const float*)d_in[10];
  const float* f2w  = (const float*)d_in[11];
  const float* f2b  = (const float*)d_in[12];
  const float* g2   = (const float*)d_in[13];
  const float* be2  = (const float*)d_in[14];
  const float* m2   = (const float*)d_in[15];
  const float* v2   = (const float*)d_in[16];
  const float* ewih = (const float*)d_in[17];
  const float* ewhh = (const float*)d_in[18];
  const float* eb   = (const float*)d_in[19];
  const float* dwih = (const float*)d_in[20];
  const float* dwhh = (const float*)d_in[21];
  const float* db   = (const float*)d_in[22];
  const float* ow   = (const float*)d_in[23];
  const float* ob   = (const float*)d_in[24];
  float* ws  = (float*)d_ws;
  h2*    wsh = (h2*)d_ws;
  float* out = (float*)d_out;

  // weight prep: 98304 items = 384 blocks x 256
  k_setup<<<384, 256, 0, stream>>>(c1w, c2w, f1w, f1b, g1, be1, m1, v1,
                                   f2w, f2b, g2, be2, m2, v2,
                                   ewih, ewhh, eb, dwih, dwhh, db, ws);
  k_transpose<<<dim3(200, 16), 256, 0, stream>>>(obs, ws + OBS_T);
  k_conv1<<<dim3(128, 25), 256, 0, stream>>>(ws + OBS_T, ws + W_C1, c1b, wsh + POOL1H);
  k_conv2h<<<dim3(128, 16), 256, 0, stream>>>(wsh + POOL1H, wsh + W_C2H, c2b, wsh + POOL2H);
  k_fc16h<<<dim3(128, 8), 256, 0, stream>>>(wsh + POOL2H, wsh + W_F1H, ws + B_F1,
                                            wsh + Y1H, 64, 128);
  k_fc16h<<<dim3(128, 4), 256, 0, stream>>>(wsh + Y1H, wsh + W_F2H, ws + B_F2,
                                            wsh + FEATSH, 64, 64);
  k_xgatesh<<<dim3(128, 16), 256, 0, stream>>>(wsh + FEATSH, wsh + W_ENCXH, ws + B_ENC,
                                               ws + GX);
  // fused encoder + decoder + output head: LDS-swizzled weights, 1-shuffle reduce
  k_seq8<<<256, 512, 0, stream>>>(ws + GX, wsh + W_ENCHH, wsh + W_DECH,
                                  ws + B_DEC, ow, ob, out);
}